// Round 4
// baseline (781.156 us; speedup 1.0000x reference)
//
#include <hip/hip_runtime.h>

#define N_NODES 50000
#define N_EDGES 800000
#define D_IN    128
#define D_E     64
#define NH      4
#define F_TOT   128          // NH * D_OUT
#define NEG_SLOPE 0.2f

typedef __attribute__((ext_vector_type(8))) short short8;   // 8 bf16
typedef __attribute__((ext_vector_type(4))) float f32x4;

__device__ __forceinline__ short f2bf(float x) {            // RNE f32->bf16
    unsigned u = __float_as_uint(x);
    u += 0x7FFFu + ((u >> 16) & 1u);
    return (short)(u >> 16);
}

// ---------------------------------------------------------------------------
// K1: node transform -> SWIZZLED layout.
//   HT_sw[n*128 + s] = HT[n][f(s)],  f(s) = (s&7)*16 + (s>>3)
// so that in k_gat, lane r16 reads its 8 features {ft*16+r16} as 2 float4s.
// Implemented by permuting the LDS weight staging only; compute/store code
// is identical to the plain version (stores stay float2-coalesced).
// ---------------------------------------------------------------------------
__global__ __launch_bounds__(256) void k_node_transform(
    const float* __restrict__ H, const float* __restrict__ W,
    float* __restrict__ HTsw)
{
    __shared__ float wt[D_IN * F_TOT];   // wt[k*128+s] = W[f(s)][k]
    const int tid = threadIdx.x;
    for (int i = tid; i < D_IN * F_TOT; i += 256) {
        const int s = i & 127, k = i >> 7;
        const int f = (s & 7) * 16 + (s >> 3);
        wt[k * F_TOT + s] = W[f * D_IN + k];
    }
    __syncthreads();

    const int l = tid & 63;
    const int w = tid >> 6;
    const int gwave  = blockIdx.x * 4 + w;
    const int nwaves = gridDim.x * 4;
    const int ngroups = N_NODES / 8;     // 6250, exact

    for (int grp = gwave; grp < ngroups; grp += nwaves) {
        const int g = grp * 8;
        float ax[8], ay[8];
#pragma unroll
        for (int j = 0; j < 8; ++j) { ax[j] = 0.f; ay[j] = 0.f; }

        for (int k4 = 0; k4 < D_IN / 4; ++k4) {
            float hv[8][4];
#pragma unroll
            for (int j = 0; j < 8; ++j)
                *(float4*)hv[j] = *(const float4*)&H[(size_t)(g + j) * D_IN + k4 * 4];
#pragma unroll
            for (int kk = 0; kk < 4; ++kk) {
                const float2 wk = *(const float2*)&wt[(k4 * 4 + kk) * F_TOT + 2 * l];
#pragma unroll
                for (int j = 0; j < 8; ++j) {
                    ax[j] = fmaf(wk.x, hv[j][kk], ax[j]);
                    ay[j] = fmaf(wk.y, hv[j][kk], ay[j]);
                }
            }
        }
#pragma unroll
        for (int j = 0; j < 8; ++j) {
            float2 r; r.x = ax[j]; r.y = ay[j];
            *(float2*)&HTsw[(size_t)(g + j) * F_TOT + 2 * l] = r;
        }
    }
}

// ---------------------------------------------------------------------------
// K2a: histogram of dst degrees
// ---------------------------------------------------------------------------
__global__ __launch_bounds__(256) void k_hist(
    const int* __restrict__ EI, int* __restrict__ deg)
{
    const int e = blockIdx.x * 256 + threadIdx.x;
    if (e < N_EDGES) atomicAdd(&deg[EI[N_EDGES + e]], 1);
}

// ---------------------------------------------------------------------------
// K2b: single-block exclusive scan of deg -> row_start[0..N], cursor copy
// ---------------------------------------------------------------------------
__global__ __launch_bounds__(1024) void k_scan(
    const int* __restrict__ deg, int* __restrict__ row_start,
    int* __restrict__ cursor)
{
    __shared__ int wsum[16];
    __shared__ int carry;
    const int tid = threadIdx.x;
    const int l = tid & 63;
    const int wv = tid >> 6;
    if (tid == 0) carry = 0;

    for (int base = 0; base < N_NODES; base += 1024) {
        __syncthreads();                       // [A] carry ready, wsum free
        const int cb = carry;
        const int i = base + tid;
        const int v = (i < N_NODES) ? deg[i] : 0;
        int x = v;                             // inclusive wave scan
#pragma unroll
        for (int off = 1; off < 64; off <<= 1) {
            int t = __shfl_up(x, off, 64);
            if (l >= off) x += t;
        }
        if (l == 63) wsum[wv] = x;
        __syncthreads();                       // [B] wsum ready
        int wave_off = 0;
        for (int k = 0; k < wv; ++k) wave_off += wsum[k];
        int tot = 0;
#pragma unroll
        for (int k = 0; k < 16; ++k) tot += wsum[k];
        const int excl = cb + wave_off + (x - v);
        if (i < N_NODES) { row_start[i] = excl; cursor[i] = excl; }
        __syncthreads();                       // [C] all read cb/wsum
        if (tid == 0) carry = cb + tot;
    }
    __syncthreads();
    if (tid == 0) row_start[N_NODES] = carry;
}

// ---------------------------------------------------------------------------
// K3: CSR permutation — one atomic per edge, write src id + edge id.
// ---------------------------------------------------------------------------
__global__ __launch_bounds__(256) void k_permute(
    const int* __restrict__ EI, int* __restrict__ cursor,
    int* __restrict__ srcperm, int* __restrict__ eidperm)
{
    const int e = blockIdx.x * 256 + threadIdx.x;
    if (e < N_EDGES) {
        const int s = EI[e];
        const int d = EI[N_EDGES + e];
        const int pos = atomicAdd(&cursor[d], 1);
        srcperm[pos] = s;
        eidperm[pos] = e;
    }
}

// ---------------------------------------------------------------------------
// K4: fused GAT pass. One wave per dst node; 16-edge tiles:
//   ET(16x128) = E_tile @ We^T via 16x mfma_f32_16x16x32_bf16 (layouts as R3,
//     verified by absmax): A[m=lane&15][k=g4*8+j], D: col=lane&15, row=g4*4+r
//   HT rows in swizzled layout -> 2 float4 loads per row per lane.
//   logit -> exp (no max shift; shift-invariant, logits bounded)
//   message + weight-sum accumulated per 16-lane group; cross-group shfl
//   reduce at the end; normalized store. ZERO global atomics here.
// ---------------------------------------------------------------------------
__global__ __launch_bounds__(256, 3) void k_gat(
    const float* __restrict__ E, const float* __restrict__ We,
    const float* __restrict__ att, const float* __restrict__ HTsw,
    const int* __restrict__ srcperm, const int* __restrict__ eidperm,
    const int* __restrict__ row_start, float* __restrict__ out)
{
    const int tid = threadIdx.x;
    const int l   = tid & 63;
    const int wv  = tid >> 6;
    const int r16 = l & 15;
    const int g4  = l >> 4;

    // register-resident B fragments: bf[ft][kc][j] = We[ft*16+r16][kc*32+g4*8+j]
    short8 bf[8][2];
#pragma unroll
    for (int ft = 0; ft < 8; ++ft) {
#pragma unroll
        for (int kc = 0; kc < 2; ++kc) {
            const float* wp = &We[(size_t)(ft * 16 + r16) * D_E + kc * 32 + g4 * 8];
            const float4 lo = *(const float4*)wp;
            const float4 hi = *(const float4*)(wp + 4);
            short8 b;
            b[0] = f2bf(lo.x); b[1] = f2bf(lo.y); b[2] = f2bf(lo.z); b[3] = f2bf(lo.w);
            b[4] = f2bf(hi.x); b[5] = f2bf(hi.y); b[6] = f2bf(hi.z); b[7] = f2bf(hi.w);
            bf[ft][kc] = b;
        }
    }
    float attv[8];
#pragma unroll
    for (int ft = 0; ft < 8; ++ft) attv[ft] = att[ft * 16 + r16];

    const int n = blockIdx.x * 4 + wv;           // grid covers exactly 50000
    if (n >= N_NODES) return;
    const int beg = row_start[n];
    const int end = row_start[n + 1];

    // dst row, loaded once (swizzled: 2x float4)
    float hdv[8];
    {
        const float4 d0 = *(const float4*)&HTsw[(size_t)n * F_TOT + r16 * 8];
        const float4 d1 = *(const float4*)&HTsw[(size_t)n * F_TOT + r16 * 8 + 4];
        hdv[0] = d0.x; hdv[1] = d0.y; hdv[2] = d0.z; hdv[3] = d0.w;
        hdv[4] = d1.x; hdv[5] = d1.y; hdv[6] = d1.z; hdv[7] = d1.w;
    }

    float macc[8];
#pragma unroll
    for (int ft = 0; ft < 8; ++ft) macc[ft] = 0.f;
    float sw4[4] = {0.f, 0.f, 0.f, 0.f};

    for (int base = beg; base < end; base += 16) {
        // indices: lanes 0..15 fetch this tile's 16 slots (clamped to beg)
        int svl = 0, evl = 0;
        if (l < 16) {
            const int idx = base + l;
            const int cidx = idx < end ? idx : beg;
            svl = srcperm[cidx];
            evl = eidperm[cidx];
        }
        // A fragments: row r16 -> E row eidperm[base+r16]
        const int eid = __shfl(evl, r16, 64);
        const float* ep = &E[(size_t)eid * D_E + g4 * 8];
        const float4 a0 = *(const float4*)ep;
        const float4 a1 = *(const float4*)(ep + 4);
        const float4 a2 = *(const float4*)(ep + 32);
        const float4 a3 = *(const float4*)(ep + 36);

        // hoist all 4 edges' HT[src] gathers (8 float4 loads in flight)
        int sidx[4];
#pragma unroll
        for (int r = 0; r < 4; ++r) sidx[r] = __shfl(svl, g4 * 4 + r, 64);
        float4 h0[4], h1[4];
#pragma unroll
        for (int r = 0; r < 4; ++r) {
            const float* hp = &HTsw[(size_t)sidx[r] * F_TOT + r16 * 8];
            h0[r] = *(const float4*)hp;
            h1[r] = *(const float4*)(hp + 4);
        }

        short8 af0, af1;
        af0[0] = f2bf(a0.x); af0[1] = f2bf(a0.y); af0[2] = f2bf(a0.z); af0[3] = f2bf(a0.w);
        af0[4] = f2bf(a1.x); af0[5] = f2bf(a1.y); af0[6] = f2bf(a1.z); af0[7] = f2bf(a1.w);
        af1[0] = f2bf(a2.x); af1[1] = f2bf(a2.y); af1[2] = f2bf(a2.z); af1[3] = f2bf(a2.w);
        af1[4] = f2bf(a3.x); af1[5] = f2bf(a3.y); af1[6] = f2bf(a3.z); af1[7] = f2bf(a3.w);

        f32x4 acc[8];
#pragma unroll
        for (int ft = 0; ft < 8; ++ft) {
            f32x4 z = {0.f, 0.f, 0.f, 0.f};
            z = __builtin_amdgcn_mfma_f32_16x16x32_bf16(af0, bf[ft][0], z, 0, 0, 0);
            acc[ft] = __builtin_amdgcn_mfma_f32_16x16x32_bf16(af1, bf[ft][1], z, 0, 0, 0);
        }

#pragma unroll
        for (int r = 0; r < 4; ++r) {
            const bool valid = (base + g4 * 4 + r) < end;
            float hsv[8];
            hsv[0] = h0[r].x; hsv[1] = h0[r].y; hsv[2] = h0[r].z; hsv[3] = h0[r].w;
            hsv[4] = h1[r].x; hsv[5] = h1[r].y; hsv[6] = h1[r].z; hsv[7] = h1[r].w;
            float ph[4] = {0.f, 0.f, 0.f, 0.f};
#pragma unroll
            for (int ft = 0; ft < 8; ++ft) {
                float v = hsv[ft] + hdv[ft] + acc[ft][r];
                v = v > 0.f ? v : NEG_SLOPE * v;
                ph[ft >> 1] = fmaf(v, attv[ft], ph[ft >> 1]);
            }
#pragma unroll
            for (int m = 1; m < 16; m <<= 1) {
#pragma unroll
                for (int hh = 0; hh < 4; ++hh)
                    ph[hh] += __shfl_xor(ph[hh], m, 64);
            }
            float wgt[4];
#pragma unroll
            for (int hh = 0; hh < 4; ++hh)
                wgt[hh] = valid ? __expf(ph[hh]) : 0.f;
#pragma unroll
            for (int ft = 0; ft < 8; ++ft)
                macc[ft] = fmaf(wgt[ft >> 1], hsv[ft], macc[ft]);
#pragma unroll
            for (int hh = 0; hh < 4; ++hh) sw4[hh] += wgt[hh];
        }
    }

    // cross-group (4x16-lane) reduction: features align across groups
#pragma unroll
    for (int mask = 16; mask < 64; mask <<= 1) {
#pragma unroll
        for (int ft = 0; ft < 8; ++ft) macc[ft] += __shfl_xor(macc[ft], mask, 64);
#pragma unroll
        for (int hh = 0; hh < 4; ++hh) sw4[hh] += __shfl_xor(sw4[hh], mask, 64);
    }
    const float inv = 1.f / (sw4[g4] + 1e-16f);   // group g4 stores head g4's cols
    const int f0 = (2 * g4) * 16 + r16;
    out[(size_t)n * F_TOT + f0]      = macc[2 * g4]     * inv;
    out[(size_t)n * F_TOT + f0 + 16] = macc[2 * g4 + 1] * inv;
}

extern "C" void kernel_launch(void* const* d_in, const int* in_sizes, int n_in,
                              void* d_out, int out_size, void* d_ws, size_t ws_size,
                              hipStream_t stream)
{
    const float* H   = (const float*)d_in[0];
    const int*   EI  = (const int*)d_in[1];
    const float* E   = (const float*)d_in[2];
    const float* W   = (const float*)d_in[3];
    const float* We  = (const float*)d_in[4];
    const float* att = (const float*)d_in[5];
    float* out = (float*)d_out;

    // workspace layout (~32.8 MB)
    float* HTsw      = (float*)d_ws;                          // 6.4M f32
    int*   srcperm   = (int*)(HTsw + (size_t)N_NODES * F_TOT);// 800k i32
    int*   eidperm   = srcperm + N_EDGES;                     // 800k i32
    int*   deg       = eidperm + N_EDGES;                     // 50k
    int*   row_start = deg + N_NODES;                         // 50k+1
    int*   cursor    = row_start + N_NODES + 1;               // 50k

    hipMemsetAsync(deg, 0, N_NODES * sizeof(int), stream);

    k_hist<<<(N_EDGES + 255) / 256, 256, 0, stream>>>(EI, deg);
    k_scan<<<1, 1024, 0, stream>>>(deg, row_start, cursor);
    k_node_transform<<<512, 256, 0, stream>>>(H, W, HTsw);
    k_permute<<<(N_EDGES + 255) / 256, 256, 0, stream>>>(EI, cursor,
                                                         srcperm, eidperm);
    k_gat<<<(N_NODES + 3) / 4, 256, 0, stream>>>(E, We, att, HTsw,
                                                 srcperm, eidperm,
                                                 row_start, out);
}